// Round 4
// baseline (1421.347 us; speedup 1.0000x reference)
//
#include <hip/hip_runtime.h>
#include <stdint.h>

// ---------- workspace layout ----------
// doubles: [0,288) binacc[3][32][3] ; [288,480) stats[3][32][2] (sum,sumsq)
// floats after 480 doubles: gb: gamma[32], beta[32]

__global__ void zero_ws(double* wsd) {
    int i = threadIdx.x;
    if (i < 480) wsd[i] = 0.0;
}

// ---------- FFT + global-stats kernel ----------
// One block per (input, batch, row-pair). 2 real rows packed into one complex 512-pt FFT.
__global__ __launch_bounds__(256) void fft_stats(const float* __restrict__ noisy,
                                                 const float* __restrict__ base,
                                                 const float* __restrict__ mem,
                                                 double* __restrict__ binacc,
                                                 double* __restrict__ stats) {
    int bid = blockIdx.x;
    int rp  = bid & 255;
    int b   = (bid >> 8) & 31;
    int iid = bid >> 13;           // 0..2
    const float* x = (iid == 0) ? noisy : (iid == 1) ? base : mem;
    const float* rowA = x + (((size_t)b << 9) + (rp << 1)) * 512;
    const float* rowB = rowA + 512;

    __shared__ float re[512], im[512];
    __shared__ float sbins[3];
    __shared__ float swsum[4], swsq[4];

    int t = threadIdx.x;
    float a0 = rowA[t], a1 = rowA[t + 256];
    float b0 = rowB[t], b1 = rowB[t + 256];

    int r0 = __brev((unsigned)t) >> 23;
    int r1 = __brev((unsigned)(t + 256)) >> 23;
    re[r0] = a0; im[r0] = b0;
    re[r1] = a1; im[r1] = b1;

    // stats partials (sum, sumsq of both rows)
    float ps = a0 + a1 + b0 + b1;
    float pq = a0 * a0 + a1 * a1 + b0 * b0 + b1 * b1;
    #pragma unroll
    for (int off = 32; off > 0; off >>= 1) {
        ps += __shfl_down(ps, off);
        pq += __shfl_down(pq, off);
    }
    if ((t & 63) == 0) { swsum[t >> 6] = ps; swsq[t >> 6] = pq; }
    if (t < 3) sbins[t] = 0.f;
    __syncthreads();

    // 9-stage radix-2 DIT FFT (bit-reversed input)
    for (int s = 1; s <= 9; ++s) {
        int h = 1 << (s - 1);
        int pos = t & (h - 1);
        int grp = t >> (s - 1);
        int i0 = (grp << s) + pos;
        int i1 = i0 + h;
        float ang = -6.2831853071795864769f * (float)pos / (float)(1 << s);
        float sn, cs;
        __sincosf(ang, &sn, &cs);
        float xr = re[i1], xi = im[i1];
        float tr = xr * cs - xi * sn;
        float ti = xr * sn + xi * cs;
        float ur = re[i0], ui = im[i0];
        re[i1] = ur - tr; im[i1] = ui - ti;
        re[i0] = ur + tr; im[i0] = ui + ti;
        __syncthreads();
    }

    // extract the two real-FFT power spectra, reduce into 3 bins
    for (int f = t; f <= 256; f += 256) {
        int nf = (512 - f) & 511;
        float zr = re[f], zi = im[f];
        float yr = re[nf], yi = im[nf];
        float ar = 0.5f * (zr + yr), ai = 0.5f * (zi - yi);
        float br = 0.5f * (zi + yi), bi = -0.5f * (zr - yr);
        float pw = ar * ar + ai * ai + br * br + bi * bi;
        int bin = (f < 85) ? 0 : ((f < 170) ? 1 : 2);
        atomicAdd(&sbins[bin], pw);
    }
    __syncthreads();
    if (t < 3) atomicAdd(&binacc[(iid * 32 + b) * 3 + t], (double)sbins[t]);
    if (t == 0) {
        float s4 = swsum[0] + swsum[1] + swsum[2] + swsum[3];
        float q4 = swsq[0] + swsq[1] + swsq[2] + swsq[3];
        atomicAdd(&stats[(iid * 32 + b) * 2 + 0], (double)s4);
        atomicAdd(&stats[(iid * 32 + b) * 2 + 1], (double)q4);
    }
}

// ---------- tiny MLP kernel: feats -> gamma/beta ----------
__global__ void mlp_k(const double* __restrict__ stats, const double* __restrict__ binacc,
                      const float* __restrict__ mw1, const float* __restrict__ mb1,
                      const float* __restrict__ mw2, const float* __restrict__ mb2,
                      float* __restrict__ gb) {
    int b = threadIdx.x;
    if (b >= 32) return;
    float feats[15];
    const double N = 262144.0;
    for (int i = 0; i < 3; ++i) {
        double s = stats[(i * 32 + b) * 2 + 0];
        double q = stats[(i * 32 + b) * 2 + 1];
        double mean = s / N;
        double var = (q - s * s / N) / (N - 1.0);
        feats[2 * i]     = (float)mean;
        feats[2 * i + 1] = sqrtf(fmaxf((float)var, 0.f));
    }
    const double cnt[3] = {85.0, 85.0, 87.0};
    for (int i = 0; i < 3; ++i) {
        float f[3]; float m = 0.f;
        for (int k = 0; k < 3; ++k) {
            f[k] = log1pf((float)(binacc[(i * 32 + b) * 3 + k] / (512.0 * cnt[k])));
            m += f[k];
        }
        m = m * (1.f / 3.f);
        for (int k = 0; k < 3; ++k) feats[6 + i * 3 + k] = f[k] / (m + 1e-6f);
    }
    float hid[16];
    for (int h = 0; h < 16; ++h) {
        float a = mb1[h];
        for (int j = 0; j < 15; ++j) a += mw1[h * 15 + j] * feats[j];
        hid[h] = fmaxf(a, 0.f);
    }
    float h0 = mb2[0], h1 = mb2[1];
    for (int j = 0; j < 16; ++j) { h0 += mw2[j] * hid[j]; h1 += mw2[16 + j] * hid[j]; }
    gb[b]      = 1.f / (1.f + expf(-h0));       // gamma
    gb[32 + b] = 0.1f * tanhf(h1);              // beta
}

// ---------- fused conv1+conv2+conv3+epilogue, all fp32 ----------
// 32x32 output tile per block. KEY: H1/H2 are zero-MASKED outside the image,
// matching the reference's per-layer SAME zero-padding (conv2 pads H1, conv3 pads H2).
__global__ __launch_bounds__(256) void conv_fused(
    const float* __restrict__ noisy, const float* __restrict__ base,
    const float* __restrict__ w1, const float* __restrict__ b1,
    const float* __restrict__ w2, const float* __restrict__ b2,
    const float* __restrict__ w3, const float* __restrict__ b3,
    const float* __restrict__ gb, float* __restrict__ out) {

    __shared__ float sH1[16 * 1296 + 8];   // 16 ch x 36x36 (stride 36), +pad: 82976 B
    __shared__ float sH2[16 * 1224];       // 16 ch x 34 rows x stride 36: 78336 B
    float* sIn = sH2;                      // overlay: 2 ch x 38 rows x stride 40 = 12160 B

    const int tid = threadIdx.x;
    const int bid = blockIdx.x;
    const int bx = bid & 15, by = (bid >> 4) & 15, b = bid >> 8;
    const int oy0 = by * 32, ox0 = bx * 32;

    // ---- stage input tile fp32 (2 ch, 38x38 in 38x40 strided, halo 3, zero-pad SAME) ----
    for (int idx = tid; idx < 2 * 38 * 38; idx += 256) {
        int ic = idx / 1444;
        int rem = idx - ic * 1444;
        int iy = rem / 38, ix = rem - iy * 38;
        int gy = oy0 + iy - 3, gx = ox0 + ix - 3;
        float v = 0.f;
        if ((unsigned)gy < 512u && (unsigned)gx < 512u)
            v = (ic ? base : noisy)[((size_t)b << 18) + (gy << 9) + gx];
        sIn[ic * 1520 + iy * 40 + ix] = v;
    }
    __syncthreads();

    const int wave = tid >> 6, lane = tid & 63;
    const int cob = wave << 2;   // 4 output channels per wave

    // ---- conv1: 2 -> 16, outputs 36x36 ----
    for (int rd = 0; rd < 3; ++rd) {
        int tI = lane + (rd << 6);
        if (tI < 180) {
            int y = tI / 5, x0 = (tI - y * 5) * 8;
            float acc[4][8];
            #pragma unroll
            for (int co = 0; co < 4; ++co) {
                float bb = b1[cob + co];
                #pragma unroll
                for (int xi = 0; xi < 8; ++xi) acc[co][xi] = bb;
            }
            #pragma unroll
            for (int ci = 0; ci < 2; ++ci)
            #pragma unroll
            for (int dy = 0; dy < 3; ++dy) {
                const float* rp_ = &sIn[ci * 1520 + (y + dy) * 40 + x0];
                float inv[10];
                float4 va = *reinterpret_cast<const float4*>(rp_);
                float4 vb = *reinterpret_cast<const float4*>(rp_ + 4);
                float2 vc = *reinterpret_cast<const float2*>(rp_ + 8);
                inv[0]=va.x; inv[1]=va.y; inv[2]=va.z; inv[3]=va.w;
                inv[4]=vb.x; inv[5]=vb.y; inv[6]=vb.z; inv[7]=vb.w;
                inv[8]=vc.x; inv[9]=vc.y;
                #pragma unroll
                for (int co = 0; co < 4; ++co) {
                    const float* wp = &w1[(((cob + co) * 2 + ci) * 3 + dy) * 3];
                    float wa = wp[0], wb = wp[1], wc = wp[2];
                    #pragma unroll
                    for (int xi = 0; xi < 8; ++xi)
                        acc[co][xi] = fmaf(wa, inv[xi], fmaf(wb, inv[xi + 1], fmaf(wc, inv[xi + 2], acc[co][xi])));
                }
            }
            // store with zero-mask outside image (conv2's SAME padding of H1)
            int gy1 = oy0 + y - 2;
            bool yin = (unsigned)gy1 < 512u;
            #pragma unroll
            for (int co = 0; co < 4; ++co)
                #pragma unroll
                for (int xi = 0; xi < 8; ++xi)
                    if (x0 + xi < 36) {
                        int gx1 = ox0 + x0 + xi - 2;
                        bool inimg = yin && ((unsigned)gx1 < 512u);
                        sH1[(cob + co) * 1296 + y * 36 + x0 + xi] = inimg ? fmaxf(acc[co][xi], 0.f) : 0.f;
                    }
        }
    }
    __syncthreads();

    // ---- conv2: 16 -> 16, outputs 34x34 (stride 36) ----
    for (int rd = 0; rd < 3; ++rd) {
        int tI = lane + (rd << 6);
        if (tI < 170) {
            int y = tI / 5, x0 = (tI - y * 5) * 8;
            float acc[4][8];
            #pragma unroll
            for (int co = 0; co < 4; ++co) {
                float bb = b2[cob + co];
                #pragma unroll
                for (int xi = 0; xi < 8; ++xi) acc[co][xi] = bb;
            }
            for (int ci = 0; ci < 16; ++ci)
            #pragma unroll
            for (int dy = 0; dy < 3; ++dy) {
                const float* rp_ = &sH1[ci * 1296 + (y + dy) * 36 + x0];
                float inv[10];
                float4 va = *reinterpret_cast<const float4*>(rp_);
                float4 vb = *reinterpret_cast<const float4*>(rp_ + 4);
                float2 vc = *reinterpret_cast<const float2*>(rp_ + 8);
                inv[0]=va.x; inv[1]=va.y; inv[2]=va.z; inv[3]=va.w;
                inv[4]=vb.x; inv[5]=vb.y; inv[6]=vb.z; inv[7]=vb.w;
                inv[8]=vc.x; inv[9]=vc.y;
                #pragma unroll
                for (int co = 0; co < 4; ++co) {
                    const float* wp = &w2[(((cob + co) * 16 + ci) * 3 + dy) * 3];
                    float wa = wp[0], wb = wp[1], wc = wp[2];
                    #pragma unroll
                    for (int xi = 0; xi < 8; ++xi)
                        acc[co][xi] = fmaf(wa, inv[xi], fmaf(wb, inv[xi + 1], fmaf(wc, inv[xi + 2], acc[co][xi])));
                }
            }
            // store with zero-mask outside image (conv3's SAME padding of H2)
            int gy2 = oy0 + y - 1;
            bool yin = (unsigned)gy2 < 512u;
            #pragma unroll
            for (int co = 0; co < 4; ++co)
                #pragma unroll
                for (int xi = 0; xi < 8; ++xi)
                    if (x0 + xi < 34) {
                        int gx2 = ox0 + x0 + xi - 1;
                        bool inimg = yin && ((unsigned)gx2 < 512u);
                        sH2[(cob + co) * 1224 + y * 36 + x0 + xi] = inimg ? fmaxf(acc[co][xi], 0.f) : 0.f;
                    }
        }
    }
    __syncthreads();

    // ---- conv3: 16 -> 1, outputs 32x32, fused epilogue ----
    {
        int y = tid >> 3, x0 = (tid & 7) * 4;   // 256 tiles of 4 outputs each
        float acc[4];
        float bb = b3[0];
        #pragma unroll
        for (int xi = 0; xi < 4; ++xi) acc[xi] = bb;
        for (int ci = 0; ci < 16; ++ci)
        #pragma unroll
        for (int dy = 0; dy < 3; ++dy) {
            const float* rp_ = &sH2[ci * 1224 + (y + dy) * 36 + x0];
            float inv[6];
            float4 va = *reinterpret_cast<const float4*>(rp_);
            float2 vb = *reinterpret_cast<const float2*>(rp_ + 4);
            inv[0]=va.x; inv[1]=va.y; inv[2]=va.z; inv[3]=va.w; inv[4]=vb.x; inv[5]=vb.y;
            const float* wp = &w3[(ci * 3 + dy) * 3];
            float wa = wp[0], wb = wp[1], wc = wp[2];
            #pragma unroll
            for (int xi = 0; xi < 4; ++xi)
                acc[xi] = fmaf(wa, inv[xi], fmaf(wb, inv[xi + 1], fmaf(wc, inv[xi + 2], acc[xi])));
        }
        float gamma = gb[b], beta = gb[32 + b];
        size_t obase = ((size_t)b << 18) + ((size_t)(oy0 + y) << 9) + ox0 + x0;
        float4 bv = *reinterpret_cast<const float4*>(&base[obase]);
        float4 ov;
        ov.x = fminf(fmaxf(bv.x + gamma * acc[0] + beta, 0.f), 1.f);
        ov.y = fminf(fmaxf(bv.y + gamma * acc[1] + beta, 0.f), 1.f);
        ov.z = fminf(fmaxf(bv.z + gamma * acc[2] + beta, 0.f), 1.f);
        ov.w = fminf(fmaxf(bv.w + gamma * acc[3] + beta, 0.f), 1.f);
        *reinterpret_cast<float4*>(&out[obase]) = ov;
    }
}

extern "C" void kernel_launch(void* const* d_in, const int* in_sizes, int n_in,
                              void* d_out, int out_size, void* d_ws, size_t ws_size,
                              hipStream_t stream) {
    const float* noisy = (const float*)d_in[0];
    const float* base  = (const float*)d_in[1];
    const float* mem   = (const float*)d_in[2];
    const float* w1  = (const float*)d_in[3];
    const float* b1  = (const float*)d_in[4];
    const float* w2  = (const float*)d_in[5];
    const float* b2  = (const float*)d_in[6];
    const float* w3  = (const float*)d_in[7];
    const float* b3  = (const float*)d_in[8];
    const float* mw1 = (const float*)d_in[9];
    const float* mb1 = (const float*)d_in[10];
    const float* mw2 = (const float*)d_in[11];
    const float* mb2 = (const float*)d_in[12];

    double* wsd = (double*)d_ws;
    double* binacc = wsd;            // 288 doubles
    double* stats  = wsd + 288;      // 192 doubles
    float*  gbuf   = (float*)(wsd + 480);  // 64 floats
    float* out = (float*)d_out;

    hipLaunchKernelGGL(zero_ws, dim3(1), dim3(512), 0, stream, wsd);
    hipLaunchKernelGGL(fft_stats, dim3(3 * 32 * 256), dim3(256), 0, stream, noisy, base, mem, binacc, stats);
    hipLaunchKernelGGL(mlp_k, dim3(1), dim3(32), 0, stream, stats, binacc, mw1, mb1, mw2, mb2, gbuf);
    hipLaunchKernelGGL(conv_fused, dim3(8192), dim3(256), 0, stream, noisy, base,
                       w1, b1, w2, b2, w3, b3, gbuf, out);
}

// Round 6
// 584.221 us; speedup vs baseline: 2.4329x; 2.4329x over previous
//
#include <hip/hip_runtime.h>
#include <stdint.h>

typedef _Float16 h8_t __attribute__((ext_vector_type(8)));
typedef _Float16 h4_t __attribute__((ext_vector_type(4)));
typedef float f32x4 __attribute__((ext_vector_type(4)));

union H8 { h8_t v; uint32_t u[4]; _Float16 h[8]; };
union H4 { h4_t v; uint32_t u[2]; _Float16 h[4]; };

// ---------- workspace layout (doubles) ----------
// [0,288) binacc[3][32][3] ; [288,480) stats[3][32][2] (sum,sumsq)

__global__ void zero_ws(double* wsd) {
    int i = threadIdx.x;
    if (i < 480)
        __hip_atomic_store(&wsd[i], 0.0, __ATOMIC_RELAXED, __HIP_MEMORY_SCOPE_AGENT);
}

// ---------- FFT + global-stats kernel ----------
__global__ __launch_bounds__(256) void fft_stats(const float* __restrict__ noisy,
                                                 const float* __restrict__ base,
                                                 const float* __restrict__ mem,
                                                 double* __restrict__ binacc,
                                                 double* __restrict__ stats) {
    int bid = blockIdx.x;
    int rp  = bid & 255;
    int b   = (bid >> 8) & 31;
    int iid = bid >> 13;           // 0..2
    const float* x = (iid == 0) ? noisy : (iid == 1) ? base : mem;
    const float* rowA = x + (((size_t)b << 9) + (rp << 1)) * 512;
    const float* rowB = rowA + 512;

    __shared__ float re[512], im[512];
    __shared__ float sbins[3];
    __shared__ float swsum[4], swsq[4];

    int t = threadIdx.x;
    float a0 = rowA[t], a1 = rowA[t + 256];
    float b0 = rowB[t], b1 = rowB[t + 256];

    int r0 = __brev((unsigned)t) >> 23;
    int r1 = __brev((unsigned)(t + 256)) >> 23;
    re[r0] = a0; im[r0] = b0;
    re[r1] = a1; im[r1] = b1;

    float ps = a0 + a1 + b0 + b1;
    float pq = a0 * a0 + a1 * a1 + b0 * b0 + b1 * b1;
    #pragma unroll
    for (int off = 32; off > 0; off >>= 1) {
        ps += __shfl_down(ps, off);
        pq += __shfl_down(pq, off);
    }
    if ((t & 63) == 0) { swsum[t >> 6] = ps; swsq[t >> 6] = pq; }
    if (t < 3) sbins[t] = 0.f;
    __syncthreads();

    for (int s = 1; s <= 9; ++s) {
        int h = 1 << (s - 1);
        int pos = t & (h - 1);
        int grp = t >> (s - 1);
        int i0 = (grp << s) + pos;
        int i1 = i0 + h;
        float ang = -6.2831853071795864769f * (float)pos / (float)(1 << s);
        float sn, cs;
        __sincosf(ang, &sn, &cs);
        float xr = re[i1], xi = im[i1];
        float tr = xr * cs - xi * sn;
        float ti = xr * sn + xi * cs;
        float ur = re[i0], ui = im[i0];
        re[i1] = ur - tr; im[i1] = ui - ti;
        re[i0] = ur + tr; im[i0] = ui + ti;
        __syncthreads();
    }

    for (int f = t; f <= 256; f += 256) {
        int nf = (512 - f) & 511;
        float zr = re[f], zi = im[f];
        float yr = re[nf], yi = im[nf];
        float ar = 0.5f * (zr + yr), ai = 0.5f * (zi - yi);
        float br = 0.5f * (zi + yi), bi = -0.5f * (zr - yr);
        float pw = ar * ar + ai * ai + br * br + bi * bi;
        int bin = (f < 85) ? 0 : ((f < 170) ? 1 : 2);
        atomicAdd(&sbins[bin], pw);
    }
    __syncthreads();
    if (t < 3) atomicAdd(&binacc[(iid * 32 + b) * 3 + t], (double)sbins[t]);
    if (t == 0) {
        float s4 = swsum[0] + swsum[1] + swsum[2] + swsum[3];
        float q4 = swsq[0] + swsq[1] + swsq[2] + swsq[3];
        atomicAdd(&stats[(iid * 32 + b) * 2 + 0], (double)s4);
        atomicAdd(&stats[(iid * 32 + b) * 2 + 1], (double)q4);
    }
}

// ---------- fused MLP + MFMA conv1+conv2+conv3 + epilogue ----------
// Each block recomputes its batch's gamma/beta in-block from the atomically-
// accumulated stats/binacc (coherent reads) -> no plain-store inter-kernel dep.
__global__ __launch_bounds__(256) void conv_fused(
    const float* __restrict__ noisy, const float* __restrict__ base,
    const float* __restrict__ w1, const float* __restrict__ b1,
    const float* __restrict__ w2, const float* __restrict__ b2,
    const float* __restrict__ w3, const float* __restrict__ b3,
    const double* __restrict__ binacc, const double* __restrict__ stats,
    const float* __restrict__ mw1, const float* __restrict__ mb1,
    const float* __restrict__ mw2, const float* __restrict__ mb2,
    float* __restrict__ out) {

    __shared__ _Float16 sH1[36 * 36 * 16];   // 41472 B
    __shared__ _Float16 sH2[34 * 34 * 16];   // 36992 B
    __shared__ float sMLP[18];               // hid[16], gamma, beta
    _Float16* sIn = sH2;                     // overlay [38][40][2] = 6080 B

    const int tid = threadIdx.x;
    const int bid = blockIdx.x;
    const int bx = bid & 15, by = (bid >> 4) & 15, b = bid >> 8;
    const int oy0 = by * 32, ox0 = bx * 32;
    const int l = tid & 63, wave = tid >> 6;
    const int g = l >> 4, c15 = l & 15;
    const int t1 = g >> 1, e8 = (g & 1) << 3;

    // ---- MLP phase A: lanes 0..15 each compute one hidden unit ----
    if (tid < 16) {
        float feats[15];
        const double N = 262144.0;
        #pragma unroll
        for (int i = 0; i < 3; ++i) {
            const double* sp = &stats[(i * 32 + b) * 2];
            double s = __hip_atomic_load(&sp[0], __ATOMIC_RELAXED, __HIP_MEMORY_SCOPE_AGENT);
            double q = __hip_atomic_load(&sp[1], __ATOMIC_RELAXED, __HIP_MEMORY_SCOPE_AGENT);
            double mean = s / N;
            double var = (q - s * s / N) / (N - 1.0);
            feats[2 * i]     = (float)mean;
            feats[2 * i + 1] = sqrtf(fmaxf((float)var, 0.f));
        }
        const double cnt[3] = {85.0, 85.0, 87.0};
        #pragma unroll
        for (int i = 0; i < 3; ++i) {
            float f[3]; float m = 0.f;
            #pragma unroll
            for (int k = 0; k < 3; ++k) {
                const double* bp = &binacc[(i * 32 + b) * 3 + k];
                double bv = __hip_atomic_load(bp, __ATOMIC_RELAXED, __HIP_MEMORY_SCOPE_AGENT);
                f[k] = log1pf((float)(bv / (512.0 * cnt[k])));
                m += f[k];
            }
            m = m * (1.f / 3.f);
            #pragma unroll
            for (int k = 0; k < 3; ++k) feats[6 + i * 3 + k] = f[k] / (m + 1e-6f);
        }
        float a = mb1[tid];
        #pragma unroll
        for (int j = 0; j < 15; ++j) a += mw1[tid * 15 + j] * feats[j];
        sMLP[tid] = fmaxf(a, 0.f);
    }

    // ---- weight fragments (A operands), VGPR-resident ----
    H8 wf1; H8 wf2[5]; H8 wf3[5];
    #pragma unroll
    for (int i = 0; i < 8; ++i) {
        int k = 8 * g + i;
        float wv = 0.f;
        if (k < 18) wv = w1[c15 * 18 + (k & 1) * 9 + (k >> 1)];
        wf1.h[i] = (_Float16)wv;
    }
    #pragma unroll
    for (int c = 0; c < 4; ++c) {
        int tap = 2 * c + t1;
        #pragma unroll
        for (int i = 0; i < 8; ++i) {
            int ci = e8 + i;
            wf2[c].h[i] = (_Float16)w2[c15 * 144 + ci * 9 + tap];
            float w3v = 0.f;
            if (c15 == 0) w3v = w3[ci * 9 + tap];
            wf3[c].h[i] = (_Float16)w3v;
        }
    }
    #pragma unroll
    for (int i = 0; i < 8; ++i) {
        float w2v = 0.f, w3v = 0.f;
        if (g < 2) {
            int ci = (g << 3) + i;
            w2v = w2[c15 * 144 + ci * 9 + 8];
            if (c15 == 0) w3v = w3[ci * 9 + 8];
        }
        wf2[4].h[i] = (_Float16)w2v;
        wf3[4].h[i] = (_Float16)w3v;
    }

    // ---- stage input tile f16 [38][40][2] (halo 3, zero-pad) ----
    {
        const float* nB = noisy + ((size_t)b << 18);
        const float* bB = base + ((size_t)b << 18);
        for (int idx = tid; idx < 38 * 38; idx += 256) {
            unsigned iy = (unsigned)idx / 38u, ix = (unsigned)idx - iy * 38u;
            int gy = oy0 + (int)iy - 3, gx = ox0 + (int)ix - 3;
            float vn = 0.f, vb = 0.f;
            if ((unsigned)gy < 512u && (unsigned)gx < 512u) {
                int o = (gy << 9) + gx;
                vn = nB[o]; vb = bB[o];
            }
            union { uint32_t u; _Float16 h[2]; } pk;
            pk.h[0] = (_Float16)vn; pk.h[1] = (_Float16)vb;
            *(uint32_t*)&sIn[((int)iy * 40 + (int)ix) * 2] = pk.u;
        }
    }
    __syncthreads();

    // ---- conv1: 2->16, 36x36 out ----
    {
        f32x4 binit;
        #pragma unroll
        for (int i = 0; i < 4; ++i) binit[i] = b1[4 * g + i];
        #pragma unroll 2
        for (int t = wave; t < 81; t += 4) {
            unsigned p = (unsigned)(t * 16 + c15);
            unsigned y1 = p / 36u, x1 = p - y1 * 36u;
            H8 bf;
            bf.u[0] = bf.u[1] = bf.u[2] = bf.u[3] = 0;
            #pragma unroll
            for (int j = 0; j < 4; ++j) {
                int tap = 4 * g + j;
                if (tap < 9) {
                    int dy = (tap * 171) >> 9;
                    int dx = tap - 3 * dy;
                    bf.u[j] = *(const uint32_t*)&sIn[((y1 + dy) * 40 + (x1 + dx)) * 2];
                }
            }
            f32x4 acc = __builtin_amdgcn_mfma_f32_16x16x32_f16(wf1.v, bf.v, binit, 0, 0, 0);
            int gy = oy0 + (int)y1 - 2, gx = ox0 + (int)x1 - 2;
            bool inimg = ((unsigned)gy < 512u) && ((unsigned)gx < 512u);
            H4 st;
            #pragma unroll
            for (int i = 0; i < 4; ++i)
                st.h[i] = inimg ? (_Float16)fmaxf(acc[i], 0.f) : (_Float16)0.f;
            *(h4_t*)&sH1[(y1 * 36 + x1) * 16 + 4 * g] = st.v;
        }
    }
    __syncthreads();

    // ---- MLP phase B: thread 0 finishes gamma/beta ----
    if (tid == 0) {
        float h0 = mb2[0], h1 = mb2[1];
        #pragma unroll
        for (int j = 0; j < 16; ++j) { h0 += mw2[j] * sMLP[j]; h1 += mw2[16 + j] * sMLP[j]; }
        sMLP[16] = 1.f / (1.f + expf(-h0));
        sMLP[17] = 0.1f * tanhf(h1);
    }

    // ---- conv2: 16->16, 34x34 out, dual-tile interleave ----
    {
        f32x4 binit;
        #pragma unroll
        for (int i = 0; i < 4; ++i) binit[i] = b2[4 * g + i];
        for (int t = wave; t < 73; t += 8) {
            int tB = t + 4;
            unsigned pA = (unsigned)(t * 16 + c15);  if (pA > 1155u) pA = 1155u;
            unsigned pB = (unsigned)(tB * 16 + c15); if (pB > 1155u) pB = 1155u;
            unsigned yA = pA / 34u, xA = pA - yA * 34u;
            unsigned yB = pB / 34u, xB = pB - yB * 34u;
            f32x4 accA = binit, accB = binit;
            #pragma unroll
            for (int c = 0; c < 5; ++c) {
                int tap = (c < 4) ? (2 * c + t1) : 8;
                int dy = (tap * 171) >> 9;
                int dx = tap - 3 * dy;
                int ci0 = (c < 4) ? e8 : (g << 3);
                H8 bfA, bfB;
                if (c == 4 && g >= 2) {
                    bfA.u[0]=bfA.u[1]=bfA.u[2]=bfA.u[3]=0;
                    bfB.u[0]=bfB.u[1]=bfB.u[2]=bfB.u[3]=0;
                } else {
                    bfA.v = *(const h8_t*)&sH1[((yA + dy) * 36 + (xA + dx)) * 16 + ci0];
                    bfB.v = *(const h8_t*)&sH1[((yB + dy) * 36 + (xB + dx)) * 16 + ci0];
                }
                accA = __builtin_amdgcn_mfma_f32_16x16x32_f16(wf2[c].v, bfA.v, accA, 0, 0, 0);
                accB = __builtin_amdgcn_mfma_f32_16x16x32_f16(wf2[c].v, bfB.v, accB, 0, 0, 0);
            }
            if ((unsigned)(t * 16 + c15) < 1156u) {
                int gy = oy0 + (int)yA - 1, gx = ox0 + (int)xA - 1;
                bool inimg = ((unsigned)gy < 512u) && ((unsigned)gx < 512u);
                H4 st;
                #pragma unroll
                for (int i = 0; i < 4; ++i)
                    st.h[i] = inimg ? (_Float16)fmaxf(accA[i], 0.f) : (_Float16)0.f;
                *(h4_t*)&sH2[(yA * 34 + xA) * 16 + 4 * g] = st.v;
            }
            if ((unsigned)(tB * 16 + c15) < 1156u) {
                int gy = oy0 + (int)yB - 1, gx = ox0 + (int)xB - 1;
                bool inimg = ((unsigned)gy < 512u) && ((unsigned)gx < 512u);
                H4 st;
                #pragma unroll
                for (int i = 0; i < 4; ++i)
                    st.h[i] = inimg ? (_Float16)fmaxf(accB[i], 0.f) : (_Float16)0.f;
                *(h4_t*)&sH2[(yB * 34 + xB) * 16 + 4 * g] = st.v;
            }
        }
    }
    __syncthreads();

    // ---- conv3: 16->1, 32x32 out, epilogue ----
    {
        float b3v = b3[0];
        float gamma = sMLP[16], beta = sMLP[17];
        for (int t = wave; t < 64; t += 8) {
            int tB = t + 4;
            unsigned pA = (unsigned)(t * 16 + c15);
            unsigned pB = (unsigned)(tB * 16 + c15);
            unsigned yA = pA >> 5, xA = pA & 31u;
            unsigned yB = pB >> 5, xB = pB & 31u;
            f32x4 accA = {b3v, b3v, b3v, b3v};
            f32x4 accB = {b3v, b3v, b3v, b3v};
            #pragma unroll
            for (int c = 0; c < 5; ++c) {
                int tap = (c < 4) ? (2 * c + t1) : 8;
                int dy = (tap * 171) >> 9;
                int dx = tap - 3 * dy;
                int ci0 = (c < 4) ? e8 : (g << 3);
                H8 bfA, bfB;
                if (c == 4 && g >= 2) {
                    bfA.u[0]=bfA.u[1]=bfA.u[2]=bfA.u[3]=0;
                    bfB.u[0]=bfB.u[1]=bfB.u[2]=bfB.u[3]=0;
                } else {
                    bfA.v = *(const h8_t*)&sH2[((yA + dy) * 34 + (xA + dx)) * 16 + ci0];
                    bfB.v = *(const h8_t*)&sH2[((yB + dy) * 34 + (xB + dx)) * 16 + ci0];
                }
                accA = __builtin_amdgcn_mfma_f32_16x16x32_f16(wf3[c].v, bfA.v, accA, 0, 0, 0);
                accB = __builtin_amdgcn_mfma_f32_16x16x32_f16(wf3[c].v, bfB.v, accB, 0, 0, 0);
            }
            if (l < 16) {  // lane holds D[co=0][pixel=l] in acc[0]
                size_t oA = ((size_t)b << 18) + ((size_t)(oy0 + yA) << 9) + (ox0 + xA);
                float o1 = fminf(fmaxf(base[oA] + gamma * accA[0] + beta, 0.f), 1.f);
                out[oA] = o1;
                size_t oB = ((size_t)b << 18) + ((size_t)(oy0 + yB) << 9) + (ox0 + xB);
                float o2 = fminf(fmaxf(base[oB] + gamma * accB[0] + beta, 0.f), 1.f);
                out[oB] = o2;
            }
        }
    }
}

extern "C" void kernel_launch(void* const* d_in, const int* in_sizes, int n_in,
                              void* d_out, int out_size, void* d_ws, size_t ws_size,
                              hipStream_t stream) {
    const float* noisy = (const float*)d_in[0];
    const float* base  = (const float*)d_in[1];
    const float* mem   = (const float*)d_in[2];
    const float* w1  = (const float*)d_in[3];
    const float* b1  = (const float*)d_in[4];
    const float* w2  = (const float*)d_in[5];
    const float* b2  = (const float*)d_in[6];
    const float* w3  = (const float*)d_in[7];
    const float* b3  = (const float*)d_in[8];
    const float* mw1 = (const float*)d_in[9];
    const float* mb1 = (const float*)d_in[10];
    const float* mw2 = (const float*)d_in[11];
    const float* mb2 = (const float*)d_in[12];

    double* wsd = (double*)d_ws;
    double* binacc = wsd;            // 288 doubles
    double* stats  = wsd + 288;      // 192 doubles
    float* out = (float*)d_out;

    hipLaunchKernelGGL(zero_ws, dim3(1), dim3(512), 0, stream, wsd);
    hipLaunchKernelGGL(fft_stats, dim3(3 * 32 * 256), dim3(256), 0, stream, noisy, base, mem, binacc, stats);
    hipLaunchKernelGGL(conv_fused, dim3(8192), dim3(256), 0, stream, noisy, base,
                       w1, b1, w2, b2, w3, b3, binacc, stats, mw1, mb1, mw2, mb2, out);
}